// Round 7
// baseline (955.282 us; speedup 1.0000x reference)
//
#include <hip/hip_runtime.h>

// LTC cell: out = states after 6 SDE unfolds of s += drift(s),
// drift = 6 ODE unfolds of v = (cm*v + gleak*vleak + num)/(cm + gleak + den).
//
// R3/R5/R6 lesson: hipcc caps arch VGPRs at 128 for big blocks; demand beyond
// that becomes AGPR moves (R5) or scratch spill (R6: 30 MB writes, 132 us
// stall). R7: fit 128 honestly -> S=8 i-splits, P = 16 float4 = 64 VGPR,
// peak live ~115. amdgpu_waves_per_eu(4,4): max=4 blocks the 8-wave/64-reg
// allocator target (R5 failure); at 128-total budget AGPRs add no capacity,
// so P stays in arch VGPRs. Keep R6's verified-good structure: lane-encoded
// split (lane=(s<<3)|jlo) -> in-wave __shfl_xor(8/16/32) reduction, dbuf v,
// ONE barrier/ODE-iter, zero main-loop VMEM, bank-conflict-free v reads.
// Floor: SIGACC = fma,exp2,add,rcp,fma,fma = 24 wave-cy/64 pairs, 1.21e9
// pairs -> 185 us. Predict 205-245 us; VGPR 96-128; WRITE ~1 MB.

#define LOG2E 1.4426950408889634f

constexpr int U   = 128;
constexpr int I   = 64;
constexpr int B   = 2048;
constexpr int M   = 4;        // batch elements per block (per thread)
constexpr int S   = 8;        // i-splits, lane bits 3..5
constexpr int BLK = U * S;    // 1024 threads = 16 waves (4/SIMD, 1 block/CU)
constexpr int RPT = U / S;    // 16 param rows per thread = 64 VGPR
constexpr int SDE = 6, ODE = 6;

#if __has_builtin(__builtin_amdgcn_exp2f)
#define EXP2(x) __builtin_amdgcn_exp2f(x)
#else
#define EXP2(x) exp2f(x)
#endif
#if __has_builtin(__builtin_amdgcn_rcpf)
#define RCP(x) __builtin_amdgcn_rcpf(x)
#else
#define RCP(x) (1.0f / (x))
#endif

// one sigmoid-accumulate pair: P = {A=-log2e*sigma, Bc=log2e*sigma*mu, W*erev, W}
#define SIGACC(P, V, PN, PD)                                   \
  {                                                            \
    float t_ = fmaf((P).x, (V), (P).y);                        \
    float e_ = EXP2(t_);                                       \
    float r_ = RCP(1.0f + e_);                                 \
    (PN) = fmaf((P).z, r_, (PN));                              \
    (PD) = fmaf((P).w, r_, (PD));                              \
  }

__global__ __launch_bounds__(256) void pack_params(
    const float* __restrict__ mu, const float* __restrict__ sigma,
    const float* __restrict__ W, const float* __restrict__ erev,
    const float* __restrict__ smu, const float* __restrict__ ssig,
    const float* __restrict__ sW, const float* __restrict__ serev,
    float4* __restrict__ pp, float4* __restrict__ ps)
{
  int idx = blockIdx.x * 256 + threadIdx.x;
  if (idx < U * U) {
    float sg = sigma[idx];
    float w  = W[idx];
    pp[idx] = make_float4(-LOG2E * sg, LOG2E * sg * mu[idx], w * erev[idx], w);
  } else if (idx < U * U + I * U) {
    int k = idx - U * U;
    float sg = ssig[k];
    float w  = sW[k];
    ps[k] = make_float4(-LOG2E * sg, LOG2E * sg * smu[k], w * serev[k], w);
  }
}

__global__ __launch_bounds__(BLK)
__attribute__((amdgpu_waves_per_eu(4, 4)))   // hard-pin: 128-VGPR budget, 4 waves/SIMD
void ltc_kernel(
    const float4* __restrict__ pp, const float4* __restrict__ ps,
    const float* __restrict__ inputs, const float* __restrict__ states,
    const float* __restrict__ iw, const float* __restrict__ ibias,
    const float* __restrict__ vleak, const float* __restrict__ gleak,
    const float* __restrict__ cmt, float* __restrict__ out)
{
  __shared__ __align__(16) float4 v4[2][M][U / 4];  // double-buffered v, 4 KB
  __shared__ __align__(16) float x_lds[M][I];       // 1 KB

  const int tid = threadIdx.x;
  const int jlo = tid & 7;
  const int s   = (tid >> 3) & 7;          // i-split id, lane bits 3..5
  const int j   = ((tid >> 6) << 3) | jlo; // output unit (wave owns 8 j's)
  const int b0  = blockIdx.x * M;

  const float cm = cmt[j];
  const float gl = gleak[j];
  const float gv = gl * vleak[j];
  const float cg = cm + gl;

  // ---- this thread's param rows i in [s*16, s*16+16) -> 16 float4 = 64 VGPR ----
  float4 P[RPT];
#pragma unroll
  for (int k = 0; k < RPT; ++k) P[k] = pp[(s * RPT + k) * U + j];

  // stage mapped input x = in*w + b into LDS
  if (tid < M * I) {
    const int m = tid >> 6, i = tid & (I - 1);
    x_lds[m][i] = inputs[(b0 + m) * I + i] * iw[i] + ibias[i];
  }
  __syncthreads();

  // ---- sensory terms (constant across unfolds); i in [s*8, s*8+8) ----
  float wns[M], wds[M];
  {
    float pn[M], pd[M];
#pragma unroll
    for (int m = 0; m < M; ++m) { pn[m] = 0.f; pd[m] = 0.f; }
#pragma unroll
    for (int q = 0; q < 2; ++q) {
      const int i = s * 8 + q * 4;
      const float4 p0 = ps[(i + 0) * U + j];
      const float4 p1 = ps[(i + 1) * U + j];
      const float4 p2 = ps[(i + 2) * U + j];
      const float4 p3 = ps[(i + 3) * U + j];
#pragma unroll
      for (int m = 0; m < M; ++m) {
        const float4 xv = *reinterpret_cast<const float4*>(&x_lds[m][i]);
        SIGACC(p0, xv.x, pn[m], pd[m]);
        SIGACC(p1, xv.y, pn[m], pd[m]);
        SIGACC(p2, xv.z, pn[m], pd[m]);
        SIGACC(p3, xv.w, pn[m], pd[m]);
      }
    }
    // in-wave combine across the 8 s-replicas (lane bits 3..5)
#pragma unroll
    for (int m = 0; m < M; ++m) {
      float n = pn[m], d = pd[m];
      n += __shfl_xor(n, 8); n += __shfl_xor(n, 16); n += __shfl_xor(n, 32);
      d += __shfl_xor(d, 8); d += __shfl_xor(d, 16); d += __shfl_xor(d, 32);
      wns[m] = n; wds[m] = d;
    }
  }

  // keep-alive pin: with a 115/128 fit this is safe, and it stops the
  // compiler from sinking the P loads into the loop (R3 failure mode).
#pragma unroll
  for (int k = 0; k < RPT; ++k)
    asm volatile("" : "+v"(P[k].x), "+v"(P[k].y), "+v"(P[k].z), "+v"(P[k].w));

  float sv[M];
#pragma unroll
  for (int m = 0; m < M; ++m) sv[m] = states[(b0 + m) * U + j];

  int buf = 0;
  float vj[M];
  for (int sde = 0; sde < SDE; ++sde) {
#pragma unroll
    for (int m = 0; m < M; ++m) vj[m] = sv[m];
    buf ^= 1;
    if (s == 0) {   // lanes 0-7 of each wave publish their 8 consecutive j's
#pragma unroll
      for (int m = 0; m < M; ++m)
        reinterpret_cast<float*>(&v4[buf][m][0])[j] = sv[m];
    }
    __syncthreads();

    for (int ode = 0; ode < ODE; ++ode) {
      float pn[M], pd[M];
#pragma unroll
      for (int m = 0; m < M; ++m) { pn[m] = 0.f; pd[m] = 0.f; }
      // main i-sweep: params from registers, v from LDS (8 addrs/wave,
      // 8-lane broadcast groups), ZERO global memory.
#pragma unroll
      for (int q = 0; q < 4; ++q) {
#pragma unroll
        for (int m = 0; m < M; ++m) {
          const float4 vv = v4[buf][m][s * 4 + q];
          SIGACC(P[q * 4 + 0], vv.x, pn[m], pd[m]);
          SIGACC(P[q * 4 + 1], vv.y, pn[m], pd[m]);
          SIGACC(P[q * 4 + 2], vv.z, pn[m], pd[m]);
          SIGACC(P[q * 4 + 3], vv.w, pn[m], pd[m]);
        }
      }
      // in-wave reduction + v-update (computed redundantly by all s-replicas)
#pragma unroll
      for (int m = 0; m < M; ++m) {
        float n = pn[m], d = pd[m];
        n += __shfl_xor(n, 8); n += __shfl_xor(n, 16); n += __shfl_xor(n, 32);
        d += __shfl_xor(d, 8); d += __shfl_xor(d, 16); d += __shfl_xor(d, 32);
        n += wns[m]; d += wds[m];
        const float den = cg + d;
        float r = RCP(den);
        r = r * (2.0f - den * r);            // one Newton step on the feedback path
        vj[m] = (fmaf(cm, vj[m], gv) + n) * r;
      }
      buf ^= 1;                               // write the OTHER buffer (WAR-safe)
      if (s == 0) {
#pragma unroll
        for (int m = 0; m < M; ++m)
          reinterpret_cast<float*>(&v4[buf][m][0])[j] = vj[m];
      }
      __syncthreads();                        // the ONLY barrier per ODE iter
    }
#pragma unroll
    for (int m = 0; m < M; ++m) sv[m] += vj[m];
  }

  if (s == 0) {
#pragma unroll
    for (int m = 0; m < M; ++m) out[(b0 + m) * U + j] = sv[m];
  }
}

extern "C" void kernel_launch(void* const* d_in, const int* in_sizes, int n_in,
                              void* d_out, int out_size, void* d_ws, size_t ws_size,
                              hipStream_t stream) {
  const float* inputs = (const float*)d_in[0];
  const float* states = (const float*)d_in[1];
  const float* iw     = (const float*)d_in[2];
  const float* ibias  = (const float*)d_in[3];
  const float* smu    = (const float*)d_in[4];
  const float* ssig   = (const float*)d_in[5];
  const float* sW     = (const float*)d_in[6];
  const float* serev  = (const float*)d_in[7];
  const float* mu     = (const float*)d_in[8];
  const float* sigma  = (const float*)d_in[9];
  const float* W      = (const float*)d_in[10];
  const float* erev   = (const float*)d_in[11];
  const float* vleak  = (const float*)d_in[12];
  const float* gleak  = (const float*)d_in[13];
  const float* cmt    = (const float*)d_in[14];
  float* out = (float*)d_out;

  // d_ws layout: packed main params (256 KB) then packed sensory params (128 KB)
  float4* pp = (float4*)d_ws;
  float4* ps = pp + U * U;

  const int packN = U * U + I * U;  // 24576
  pack_params<<<(packN + 255) / 256, 256, 0, stream>>>(
      mu, sigma, W, erev, smu, ssig, sW, serev, pp, ps);
  ltc_kernel<<<B / M, BLK, 0, stream>>>(
      pp, ps, inputs, states, iw, ibias, vleak, gleak, cmt, out);
}

// Round 11
// 543.169 us; speedup vs baseline: 1.7587x; 1.7587x over previous
//
#include <hip/hip_runtime.h>

// LTC cell: out = states after 6 SDE unfolds of s += drift(s),
// drift = 6 ODE unfolds of v = (cm*v + gleak*vleak + num)/(cm + gleak + den).
//
// Allocator law (R3/R5/R6/R7): 512-thr block -> 128 arch VGPRs, 1024-thr ->
// 64; exceeding the cap = AGPR moves or scratch (R7: 368 MB, 897 us). R8:
// design INSIDE 128 VGPRs. Params are NOT register-resident: reloaded from
// L2 each ODE iter (R3's graceful mode), but M=8 batch/thread halves that
// traffic (2.36 GB total ~64 us of L2 BW, hidden under the 123 us trans
// floor). Live regs ~100: 4 param float4 transient + 6x8 accumulators.
// Structure (verified correct in R6/R7): lane=(s<<4)|jlo -> in-wave
// __shfl_xor(16/32) reduction, double-buffered v in LDS, ONE barrier/ODE
// iter. New: s-INTERLEAVED rows (i = q*16+s*4+r) -> the 4 s-replicas read 4
// consecutive float4 of v = bank-conflict-free (blocked mapping aliased).
// Floor: SIGACC = fma,exp2,add,rcp,fma,fma; trans pipe 123 us, issue 185 us.
// Predict 190-230 us; VGPR 100-128; WRITE <=2 MB (spill tripwire).

#define LOG2E 1.4426950408889634f

constexpr int U   = 128;
constexpr int I   = 64;
constexpr int B   = 2048;
constexpr int M   = 8;        // batch elements per thread (param-reload amortizer)
constexpr int S   = 4;        // i-splits, lane bits 4-5
constexpr int BLK = 512;      // 8 waves; wave = 16 j x 4 s
constexpr int SDE = 6, ODE = 6;

#if __has_builtin(__builtin_amdgcn_exp2f)
#define EXP2(x) __builtin_amdgcn_exp2f(x)
#else
#define EXP2(x) exp2f(x)
#endif
#if __has_builtin(__builtin_amdgcn_rcpf)
#define RCP(x) __builtin_amdgcn_rcpf(x)
#else
#define RCP(x) (1.0f / (x))
#endif

// one sigmoid-accumulate pair: P = {A=-log2e*sigma, Bc=log2e*sigma*mu, W*erev, W}
#define SIGACC(P, V, PN, PD)                                   \
  {                                                            \
    float t_ = fmaf((P).x, (V), (P).y);                        \
    float e_ = EXP2(t_);                                       \
    float r_ = RCP(1.0f + e_);                                 \
    (PN) = fmaf((P).z, r_, (PN));                              \
    (PD) = fmaf((P).w, r_, (PD));                              \
  }

__global__ __launch_bounds__(256) void pack_params(
    const float* __restrict__ mu, const float* __restrict__ sigma,
    const float* __restrict__ W, const float* __restrict__ erev,
    const float* __restrict__ smu, const float* __restrict__ ssig,
    const float* __restrict__ sW, const float* __restrict__ serev,
    float4* __restrict__ pp, float4* __restrict__ ps)
{
  int idx = blockIdx.x * 256 + threadIdx.x;
  if (idx < U * U) {
    float sg = sigma[idx];
    float w  = W[idx];
    pp[idx] = make_float4(-LOG2E * sg, LOG2E * sg * mu[idx], w * erev[idx], w);
  } else if (idx < U * U + I * U) {
    int k = idx - U * U;
    float sg = ssig[k];
    float w  = sW[k];
    ps[k] = make_float4(-LOG2E * sg, LOG2E * sg * smu[k], w * serev[k], w);
  }
}

__global__ __launch_bounds__(BLK, 2) void ltc_kernel(
    const float4* __restrict__ pp, const float4* __restrict__ ps,
    const float* __restrict__ inputs, const float* __restrict__ states,
    const float* __restrict__ iw, const float* __restrict__ ibias,
    const float* __restrict__ vleak, const float* __restrict__ gleak,
    const float* __restrict__ cmt, float* __restrict__ out)
{
  __shared__ __align__(16) float4 v4[2][M][U / 4];  // double-buffered v, 8 KB
  __shared__ __align__(16) float x_lds[M][I];       // 2 KB

  const int tid = threadIdx.x;
  const int jlo = tid & 15;
  const int s   = (tid >> 4) & 3;           // i-split id, lane bits 4-5
  const int j   = ((tid >> 6) << 4) | jlo;  // output unit (wave owns 16 j's)
  const int b0  = blockIdx.x * M;

  const float cm = cmt[j];
  const float gl = gleak[j];
  const float gv = gl * vleak[j];
  const float cg = cm + gl;

  // stage mapped input x = in*w + b into LDS (512 threads = M*I exactly)
  {
    const int m = tid >> 6, i = tid & (I - 1);
    x_lds[m][i] = inputs[(b0 + m) * I + i] * iw[i] + ibias[i];
  }
  __syncthreads();

  // ---- sensory terms (constant across unfolds); rows i = q*16 + s*4 + r ----
  float wns[M], wds[M];
  {
    float pn[M], pd[M];
#pragma unroll
    for (int m = 0; m < M; ++m) { pn[m] = 0.f; pd[m] = 0.f; }
#pragma unroll
    for (int q = 0; q < I / 16; ++q) {
      const int i0 = q * 16 + s * 4;
      const float4 p0 = ps[(i0 + 0) * U + j];
      const float4 p1 = ps[(i0 + 1) * U + j];
      const float4 p2 = ps[(i0 + 2) * U + j];
      const float4 p3 = ps[(i0 + 3) * U + j];
#pragma unroll
      for (int m = 0; m < M; ++m) {
        const float4 xv = *reinterpret_cast<const float4*>(&x_lds[m][i0]);
        SIGACC(p0, xv.x, pn[m], pd[m]);
        SIGACC(p1, xv.y, pn[m], pd[m]);
        SIGACC(p2, xv.z, pn[m], pd[m]);
        SIGACC(p3, xv.w, pn[m], pd[m]);
      }
    }
    // in-wave combine across the 4 s-replicas (lane bits 4-5)
#pragma unroll
    for (int m = 0; m < M; ++m) {
      float n = pn[m], d = pd[m];
      n += __shfl_xor(n, 16); n += __shfl_xor(n, 32);
      d += __shfl_xor(d, 16); d += __shfl_xor(d, 32);
      wns[m] = n; wds[m] = d;
    }
  }

  float sv[M];
#pragma unroll
  for (int m = 0; m < M; ++m) sv[m] = states[(b0 + m) * U + j];

  int buf = 0;
  float vj[M];
  for (int sde = 0; sde < SDE; ++sde) {
#pragma unroll
    for (int m = 0; m < M; ++m) vj[m] = sv[m];
    buf ^= 1;
    if (s == 0) {   // lanes with s==0 publish all 128 j's
#pragma unroll
      for (int m = 0; m < M; ++m)
        reinterpret_cast<float*>(&v4[buf][m][0])[j] = sv[m];
    }
    __syncthreads();

    for (int ode = 0; ode < ODE; ++ode) {
      float pn[M], pd[M];
#pragma unroll
      for (int m = 0; m < M; ++m) { pn[m] = 0.f; pd[m] = 0.f; }
      // main i-sweep: 4 param float4 reloads per q (coalesced, L2-resident;
      // 8x m-reuse in registers), v from LDS: the 4 s-replicas read 4
      // CONSECUTIVE float4 -> conflict-free, 16-lane broadcast.
#pragma unroll
      for (int q = 0; q < U / 16; ++q) {
        const int i0 = q * 16 + s * 4;
        const float4 p0 = pp[(i0 + 0) * U + j];
        const float4 p1 = pp[(i0 + 1) * U + j];
        const float4 p2 = pp[(i0 + 2) * U + j];
        const float4 p3 = pp[(i0 + 3) * U + j];
#pragma unroll
        for (int m = 0; m < M; ++m) {
          const float4 vv = v4[buf][m][q * 4 + s];
          SIGACC(p0, vv.x, pn[m], pd[m]);
          SIGACC(p1, vv.y, pn[m], pd[m]);
          SIGACC(p2, vv.z, pn[m], pd[m]);
          SIGACC(p3, vv.w, pn[m], pd[m]);
        }
      }
      // in-wave reduction + v-update (redundant across s-replicas)
#pragma unroll
      for (int m = 0; m < M; ++m) {
        float n = pn[m], d = pd[m];
        n += __shfl_xor(n, 16); n += __shfl_xor(n, 32);
        d += __shfl_xor(d, 16); d += __shfl_xor(d, 32);
        n += wns[m]; d += wds[m];
        const float den = cg + d;
        float r = RCP(den);
        r = r * (2.0f - den * r);            // one Newton step on the feedback path
        vj[m] = (fmaf(cm, vj[m], gv) + n) * r;
      }
      buf ^= 1;                               // write the OTHER buffer (WAR-safe)
      if (s == 0) {
#pragma unroll
        for (int m = 0; m < M; ++m)
          reinterpret_cast<float*>(&v4[buf][m][0])[j] = vj[m];
      }
      __syncthreads();                        // the ONLY barrier per ODE iter
    }
#pragma unroll
    for (int m = 0; m < M; ++m) sv[m] += vj[m];
  }

  if (s == 0) {
#pragma unroll
    for (int m = 0; m < M; ++m) out[(b0 + m) * U + j] = sv[m];
  }
}

extern "C" void kernel_launch(void* const* d_in, const int* in_sizes, int n_in,
                              void* d_out, int out_size, void* d_ws, size_t ws_size,
                              hipStream_t stream) {
  const float* inputs = (const float*)d_in[0];
  const float* states = (const float*)d_in[1];
  const float* iw     = (const float*)d_in[2];
  const float* ibias  = (const float*)d_in[3];
  const float* smu    = (const float*)d_in[4];
  const float* ssig   = (const float*)d_in[5];
  const float* sW     = (const float*)d_in[6];
  const float* serev  = (const float*)d_in[7];
  const float* mu     = (const float*)d_in[8];
  const float* sigma  = (const float*)d_in[9];
  const float* W      = (const float*)d_in[10];
  const float* erev   = (const float*)d_in[11];
  const float* vleak  = (const float*)d_in[12];
  const float* gleak  = (const float*)d_in[13];
  const float* cmt    = (const float*)d_in[14];
  float* out = (float*)d_out;

  // d_ws layout: packed main params (256 KB) then packed sensory params (128 KB)
  float4* pp = (float4*)d_ws;
  float4* ps = pp + U * U;

  const int packN = U * U + I * U;  // 24576
  pack_params<<<(packN + 255) / 256, 256, 0, stream>>>(
      mu, sigma, W, erev, smu, ssig, sW, serev, pp, ps);
  ltc_kernel<<<B / M, BLK, 0, stream>>>(
      pp, ps, inputs, states, iw, ibias, vleak, gleak, cmt, out);
}

// Round 15
// 412.978 us; speedup vs baseline: 2.3132x; 1.3152x over previous
//
#include <hip/hip_runtime.h>

// LTC cell: out = states after 6 SDE unfolds of s += drift(s),
// drift = 6 ODE unfolds of v = (cm*v + gleak*vleak + num)/(cm + gleak + den).
//
// R11 post-mortem: M=8 spilled (VGPR=128 cap + 216 MB scratch writes,
// 791 MB scratch reads, 491 us). M=4 is the proven no-spill point (R3:
// 311 us, VALUBusy 80%, WRITE 1 KB). R12 = R3's register regime + the
// structural wins R8 carried but never got to demonstrate:
//   - in-wave __shfl_xor(16/32) reduction (lane=(s<<4)|jlo) -> no part[]
//     LDS array, no second barrier per ODE iter;
//   - double-buffered v in LDS -> exactly ONE __syncthreads per ODE iter
//     (R3 had 2);
//   - s-INTERLEAVED v rows (i = q*16+s*4+r): the 4 s-replicas read 4
//     consecutive float4 -> conflict-free 16-lane-broadcast b128 reads.
// Params stream from L2 per iter (R3's graceful mode, 4.7 GB @ ~15 TB/s
// aggregate); persistent regs = 24 (pn/pd/wns/wds/sv/vj at M=4), transient
// param float4 x4 -> ~70 live, far under the 128 cap.
// Floor: SIGACC = fma,exp2,add,rcp,fma,fma = 24 issue-cy/pair-wave ->
// 185 us + ~50 us reduction/update. Predict 260-295 us; WRITE <=2 MB.

#define LOG2E 1.4426950408889634f

constexpr int U   = 128;
constexpr int I   = 64;
constexpr int B   = 2048;
constexpr int M   = 4;        // batch elements per thread (R3's proven no-spill point)
constexpr int S   = 4;        // i-splits, lane bits 4-5
constexpr int BLK = 512;      // 8 waves; wave = 16 j x 4 s
constexpr int SDE = 6, ODE = 6;

#if __has_builtin(__builtin_amdgcn_exp2f)
#define EXP2(x) __builtin_amdgcn_exp2f(x)
#else
#define EXP2(x) exp2f(x)
#endif
#if __has_builtin(__builtin_amdgcn_rcpf)
#define RCP(x) __builtin_amdgcn_rcpf(x)
#else
#define RCP(x) (1.0f / (x))
#endif

// one sigmoid-accumulate pair: P = {A=-log2e*sigma, Bc=log2e*sigma*mu, W*erev, W}
#define SIGACC(P, V, PN, PD)                                   \
  {                                                            \
    float t_ = fmaf((P).x, (V), (P).y);                        \
    float e_ = EXP2(t_);                                       \
    float r_ = RCP(1.0f + e_);                                 \
    (PN) = fmaf((P).z, r_, (PN));                              \
    (PD) = fmaf((P).w, r_, (PD));                              \
  }

__global__ __launch_bounds__(256) void pack_params(
    const float* __restrict__ mu, const float* __restrict__ sigma,
    const float* __restrict__ W, const float* __restrict__ erev,
    const float* __restrict__ smu, const float* __restrict__ ssig,
    const float* __restrict__ sW, const float* __restrict__ serev,
    float4* __restrict__ pp, float4* __restrict__ ps)
{
  int idx = blockIdx.x * 256 + threadIdx.x;
  if (idx < U * U) {
    float sg = sigma[idx];
    float w  = W[idx];
    pp[idx] = make_float4(-LOG2E * sg, LOG2E * sg * mu[idx], w * erev[idx], w);
  } else if (idx < U * U + I * U) {
    int k = idx - U * U;
    float sg = ssig[k];
    float w  = sW[k];
    ps[k] = make_float4(-LOG2E * sg, LOG2E * sg * smu[k], w * serev[k], w);
  }
}

__global__ __launch_bounds__(BLK, 2) void ltc_kernel(
    const float4* __restrict__ pp, const float4* __restrict__ ps,
    const float* __restrict__ inputs, const float* __restrict__ states,
    const float* __restrict__ iw, const float* __restrict__ ibias,
    const float* __restrict__ vleak, const float* __restrict__ gleak,
    const float* __restrict__ cmt, float* __restrict__ out)
{
  __shared__ __align__(16) float4 v4[2][M][U / 4];  // double-buffered v, 4 KB
  __shared__ __align__(16) float x_lds[M][I];       // 1 KB

  const int tid = threadIdx.x;
  const int jlo = tid & 15;
  const int s   = (tid >> 4) & 3;           // i-split id, lane bits 4-5
  const int j   = ((tid >> 6) << 4) | jlo;  // output unit (wave owns 16 j's)
  const int b0  = blockIdx.x * M;

  const float cm = cmt[j];
  const float gl = gleak[j];
  const float gv = gl * vleak[j];
  const float cg = cm + gl;

  // stage mapped input x = in*w + b into LDS
  if (tid < M * I) {
    const int m = tid >> 6, i = tid & (I - 1);
    x_lds[m][i] = inputs[(b0 + m) * I + i] * iw[i] + ibias[i];
  }
  __syncthreads();

  // ---- sensory terms (constant across unfolds); rows i = q*16 + s*4 + r ----
  float wns[M], wds[M];
  {
    float pn[M], pd[M];
#pragma unroll
    for (int m = 0; m < M; ++m) { pn[m] = 0.f; pd[m] = 0.f; }
#pragma unroll
    for (int q = 0; q < I / 16; ++q) {
      const int i0 = q * 16 + s * 4;
      const float4 p0 = ps[(i0 + 0) * U + j];
      const float4 p1 = ps[(i0 + 1) * U + j];
      const float4 p2 = ps[(i0 + 2) * U + j];
      const float4 p3 = ps[(i0 + 3) * U + j];
#pragma unroll
      for (int m = 0; m < M; ++m) {
        const float4 xv = *reinterpret_cast<const float4*>(&x_lds[m][i0]);
        SIGACC(p0, xv.x, pn[m], pd[m]);
        SIGACC(p1, xv.y, pn[m], pd[m]);
        SIGACC(p2, xv.z, pn[m], pd[m]);
        SIGACC(p3, xv.w, pn[m], pd[m]);
      }
    }
    // in-wave combine across the 4 s-replicas (lane bits 4-5)
#pragma unroll
    for (int m = 0; m < M; ++m) {
      float n = pn[m], d = pd[m];
      n += __shfl_xor(n, 16); n += __shfl_xor(n, 32);
      d += __shfl_xor(d, 16); d += __shfl_xor(d, 32);
      wns[m] = n; wds[m] = d;
    }
  }

  float sv[M];
#pragma unroll
  for (int m = 0; m < M; ++m) sv[m] = states[(b0 + m) * U + j];

  int buf = 0;
  float vj[M];
  for (int sde = 0; sde < SDE; ++sde) {
#pragma unroll
    for (int m = 0; m < M; ++m) vj[m] = sv[m];
    buf ^= 1;
    if (s == 0) {   // lanes with s==0 publish all 128 j's
#pragma unroll
      for (int m = 0; m < M; ++m)
        reinterpret_cast<float*>(&v4[buf][m][0])[j] = sv[m];
    }
    __syncthreads();

    for (int ode = 0; ode < ODE; ++ode) {
      float pn[M], pd[M];
#pragma unroll
      for (int m = 0; m < M; ++m) { pn[m] = 0.f; pd[m] = 0.f; }
      // main i-sweep: 4 param float4 reloads per q (coalesced, L2-resident;
      // 4x m-reuse in registers), v from LDS: the 4 s-replicas read 4
      // CONSECUTIVE float4 -> conflict-free, 16-lane broadcast.
#pragma unroll
      for (int q = 0; q < U / 16; ++q) {
        const int i0 = q * 16 + s * 4;
        const float4 p0 = pp[(i0 + 0) * U + j];
        const float4 p1 = pp[(i0 + 1) * U + j];
        const float4 p2 = pp[(i0 + 2) * U + j];
        const float4 p3 = pp[(i0 + 3) * U + j];
#pragma unroll
        for (int m = 0; m < M; ++m) {
          const float4 vv = v4[buf][m][q * 4 + s];
          SIGACC(p0, vv.x, pn[m], pd[m]);
          SIGACC(p1, vv.y, pn[m], pd[m]);
          SIGACC(p2, vv.z, pn[m], pd[m]);
          SIGACC(p3, vv.w, pn[m], pd[m]);
        }
      }
      // in-wave reduction + v-update (redundant across s-replicas)
#pragma unroll
      for (int m = 0; m < M; ++m) {
        float n = pn[m], d = pd[m];
        n += __shfl_xor(n, 16); n += __shfl_xor(n, 32);
        d += __shfl_xor(d, 16); d += __shfl_xor(d, 32);
        n += wns[m]; d += wds[m];
        const float den = cg + d;
        float r = RCP(den);
        r = r * (2.0f - den * r);            // one Newton step on the feedback path
        vj[m] = (fmaf(cm, vj[m], gv) + n) * r;
      }
      buf ^= 1;                               // write the OTHER buffer (WAR-safe)
      if (s == 0) {
#pragma unroll
        for (int m = 0; m < M; ++m)
          reinterpret_cast<float*>(&v4[buf][m][0])[j] = vj[m];
      }
      __syncthreads();                        // the ONLY barrier per ODE iter
    }
#pragma unroll
    for (int m = 0; m < M; ++m) sv[m] += vj[m];
  }

  if (s == 0) {
#pragma unroll
    for (int m = 0; m < M; ++m) out[(b0 + m) * U + j] = sv[m];
  }
}

extern "C" void kernel_launch(void* const* d_in, const int* in_sizes, int n_in,
                              void* d_out, int out_size, void* d_ws, size_t ws_size,
                              hipStream_t stream) {
  const float* inputs = (const float*)d_in[0];
  const float* states = (const float*)d_in[1];
  const float* iw     = (const float*)d_in[2];
  const float* ibias  = (const float*)d_in[3];
  const float* smu    = (const float*)d_in[4];
  const float* ssig   = (const float*)d_in[5];
  const float* sW     = (const float*)d_in[6];
  const float* serev  = (const float*)d_in[7];
  const float* mu     = (const float*)d_in[8];
  const float* sigma  = (const float*)d_in[9];
  const float* W      = (const float*)d_in[10];
  const float* erev   = (const float*)d_in[11];
  const float* vleak  = (const float*)d_in[12];
  const float* gleak  = (const float*)d_in[13];
  const float* cmt    = (const float*)d_in[14];
  float* out = (float*)d_out;

  // d_ws layout: packed main params (256 KB) then packed sensory params (128 KB)
  float4* pp = (float4*)d_ws;
  float4* ps = pp + U * U;

  const int packN = U * U + I * U;  // 24576
  pack_params<<<(packN + 255) / 256, 256, 0, stream>>>(
      mu, sigma, W, erev, smu, ssig, sW, serev, pp, ps);
  ltc_kernel<<<B / M, BLK, 0, stream>>>(
      pp, ps, inputs, states, iw, ibias, vleak, gleak, cmt, out);
}